// Round 5
// baseline (457.410 us; speedup 1.0000x reference)
//
#include <hip/hip_runtime.h>
#include <hip/hip_bf16.h>
#include <hip/hip_fp16.h>

#define FEAT 128

typedef __attribute__((ext_vector_type(8))) short short8;
typedef __attribute__((ext_vector_type(4))) float f32x4;

static __device__ __forceinline__ unsigned short f2bf(float f) {
    unsigned int u = __float_as_uint(f);
    unsigned int r = (u + 0x7fffu + ((u >> 16) & 1u)) >> 16;
    return (unsigned short)r;
}
static __device__ __forceinline__ float bf2f(unsigned short b) {
    return __uint_as_float(((unsigned int)b) << 16);
}

// ---- CSR build -------------------------------------------------------------
// Fixed-capacity bucket scatter (round 10): binit(bcur[b]=b*CAP) ->
// bucket_scatter -> bscan(782 totals) -> bucket_fill2 (LDS hist + scan ->
// dinv, indptr, ssrc). No global histogram, no 100k scan.

#define BKT_SHIFT 7
#define BKT_G 128
#define MAX_NB 1024
#define BCAP 4096
#define SC_T 32
#define SC_EPB (256 * SC_T)   // 8192 edges per block

__global__ void binit_kernel(int* __restrict__ bcur, int NB) {
    int b = blockIdx.x * 256 + threadIdx.x;
    if (b < NB) bcur[b] = b * BCAP;
}

__global__ __launch_bounds__(256)
void bucket_scatter_kernel(const int* __restrict__ src, const int* __restrict__ dst,
                           int* __restrict__ bcur, unsigned int* __restrict__ tmp,
                           int E, int NB) {
    __shared__ int hist[MAX_NB];
    const int tid = threadIdx.x;
    const int ebase = blockIdx.x * SC_EPB;

    for (int i = tid; i < NB; i += 256) hist[i] = 0;
    __syncthreads();

    unsigned int pk[SC_T];    // packed (src,dst_local)
    unsigned int meta[SC_T];  // (bucket<<16) | local_rank ; 0xFFFFFFFF = invalid
    #pragma unroll
    for (int j = 0; j < SC_T; ++j) {
        int e = ebase + j * 256 + tid;
        if (e < E) {
            int s = src[e], d = dst[e];
            int b = d >> BKT_SHIFT;
            pk[j] = ((unsigned int)s << BKT_SHIFT) | (unsigned int)(d & (BKT_G - 1));
            int r = atomicAdd(&hist[b], 1);
            meta[j] = ((unsigned int)b << 16) | (unsigned int)r;
        } else {
            meta[j] = 0xFFFFFFFFu;
        }
    }
    __syncthreads();

    // one global atomic per (block,bucket); stash base back into hist
    for (int b = tid; b < NB; b += 256) {
        int c = hist[b];
        if (c > 0) hist[b] = atomicAdd(&bcur[b], c);
    }
    __syncthreads();

    #pragma unroll
    for (int j = 0; j < SC_T; ++j) {
        if (meta[j] != 0xFFFFFFFFu) {
            int b = meta[j] >> 16;
            int r = (int)(meta[j] & 0xFFFFu);
            tmp[hist[b] + r] = pk[j];
        }
    }
}

// exclusive scan of the 782 bucket totals (bcur[b]-b*CAP); writes bbase[0..NB]
// and indptr[n]=E. Single block, 1024 threads (NB <= 1024).
__global__ __launch_bounds__(1024)
void bscan_kernel(const int* __restrict__ bcur, int* __restrict__ bbase,
                  int* __restrict__ indptr, int n, int NB, int E) {
    __shared__ int swave[16];
    int tid = threadIdx.x, lane = tid & 63, wid = tid >> 6;
    int c = (tid < NB) ? (bcur[tid] - tid * BCAP) : 0;
    int x = c;
    #pragma unroll
    for (int off = 1; off < 64; off <<= 1) {
        int y = __shfl_up(x, off);
        if (lane >= off) x += y;
    }
    if (lane == 63) swave[wid] = x;
    __syncthreads();
    if (wid == 0 && lane < 16) {
        int s = swave[lane];
        #pragma unroll
        for (int off = 1; off < 16; off <<= 1) {
            int y = __shfl_up(s, off);
            if (lane >= off) s += y;
        }
        swave[lane] = s;
    }
    __syncthreads();
    int waveoff = (wid > 0) ? swave[wid - 1] : 0;
    if (tid <= NB) bbase[tid] = waveoff + x - c;   // exclusive prefix
    if (tid == 0) indptr[n] = E;
}

// block b: count local dst in LDS, emit dinv+indptr, scan, scatter ssrc.
__global__ __launch_bounds__(256)
void bucket_fill2_kernel(const unsigned int* __restrict__ tmp, const int* __restrict__ bbase,
                         int* __restrict__ indptr, float* __restrict__ dinv,
                         int* __restrict__ ssrc, int n) {
    __shared__ int cnt[BKT_G];
    __shared__ int cur[BKT_G];
    __shared__ int wtot;
    const int tid = threadIdx.x;
    const int b = blockIdx.x;
    const int nodebase = b * BKT_G;
    const int base_g = bbase[b];
    const int scnt = bbase[b + 1] - base_g;
    const unsigned int* tp = tmp + (size_t)b * BCAP;

    if (tid < BKT_G) cnt[tid] = 0;
    __syncthreads();
    for (int e = tid; e < scnt; e += 256)
        atomicAdd(&cnt[tp[e] & (BKT_G - 1)], 1);
    __syncthreads();

    int c = 0, x = 0;
    if (tid < BKT_G) {
        int lane = tid & 63;
        c = cnt[tid];
        x = c;
        #pragma unroll
        for (int off = 1; off < 64; off <<= 1) {
            int y = __shfl_up(x, off);
            if (lane >= off) x += y;
        }
    }
    if (tid == 63) wtot = x;   // wave0 inclusive total
    __syncthreads();
    if (tid < BKT_G) {
        int excl = x - c + ((tid >= 64) ? wtot : 0);
        int node = nodebase + tid;
        if (node < n) {
            dinv[node]   = rsqrtf((float)(c + 1));
            indptr[node] = base_g + excl;
        }
        cur[tid] = base_g + excl;
    }
    __syncthreads();
    for (int e = tid; e < scnt; e += 256) {
        unsigned int v = tp[e];
        int pos = atomicAdd(&cur[v & (BKT_G - 1)], 1);
        ssrc[pos] = (int)(v >> BKT_SHIFT);
    }
}

// ---- bf16x2 split prep -----------------------------------------------------

__global__ void split_kernel(const float* __restrict__ in, unsigned short* __restrict__ xh,
                             unsigned short* __restrict__ xl, int total4) {
    int i = blockIdx.x * 256 + threadIdx.x;
    if (i >= total4) return;
    float4 v = ((const float4*)in)[i];
    ushort4 h, l;
    h.x = f2bf(v.x); l.x = f2bf(v.x - bf2f(h.x));
    h.y = f2bf(v.y); l.y = f2bf(v.y - bf2f(h.y));
    h.z = f2bf(v.z); l.z = f2bf(v.z - bf2f(h.z));
    h.w = f2bf(v.w); l.w = f2bf(v.w - bf2f(h.w));
    ((ushort4*)xh)[i] = h;
    ((ushort4*)xl)[i] = l;
}

__global__ void wprep_kernel(const float* __restrict__ W1, const float* __restrict__ W2,
                             const float* __restrict__ W3, unsigned short* __restrict__ wth,
                             unsigned short* __restrict__ wtl) {
    int idx = blockIdx.x * 256 + threadIdx.x;   // 3 * 16384
    int l = idx >> 14, t = idx & 16383;
    int nn = t >> 7, kk = t & 127;
    const float* W = (l == 0) ? W1 : (l == 1) ? W2 : W3;
    float v = W[kk * 128 + nn];
    unsigned short h = f2bf(v);
    wth[idx] = h;
    wtl[idx] = f2bf(v - bf2f(h));
}

// ---- GEMM (split-bf16 MFMA, B staged in LDS): hs = (in @ W) * dinv, fp16 out

__global__ __launch_bounds__(256)
void gemm_mfma(const unsigned short* __restrict__ xh, const unsigned short* __restrict__ xl,
               const unsigned short* __restrict__ wth, const unsigned short* __restrict__ wtl,
               const float* __restrict__ dinv, __half* __restrict__ hs, int n) {
    __shared__ unsigned short bh[128][136];
    __shared__ unsigned short bl[128][136];

    const int tid = threadIdx.x;
    const int wave = tid >> 6, lane = tid & 63;
    const int rowbase = blockIdx.x * 64 + wave * 16;
    const int m = lane & 15, kg = lane >> 4;

    // stage B: thread -> row n0 = tid>>1, half kk0 = (tid&1)*64
    {
        const int n0 = tid >> 1, kk0 = (tid & 1) * 64;
        const unsigned short* gh = wth + (size_t)n0 * FEAT + kk0;
        const unsigned short* gl = wtl + (size_t)n0 * FEAT + kk0;
        #pragma unroll
        for (int j = 0; j < 8; ++j) {
            *(short8*)&bh[n0][kk0 + j * 8] = *(const short8*)(gh + j * 8);
            *(short8*)&bl[n0][kk0 + j * 8] = *(const short8*)(gl + j * 8);
        }
    }

    // A fragments (loaded while staging is in flight)
    int arow = rowbase + m;
    if (arow > n - 1) arow = n - 1;          // clamp; clamped rows never stored
    const size_t aoff = (size_t)arow * FEAT + kg * 8;
    short8 avh[4], avl[4];
    #pragma unroll
    for (int s = 0; s < 4; ++s) {
        avh[s] = *(const short8*)(xh + aoff + s * 32);
        avl[s] = *(const short8*)(xl + aoff + s * 32);
    }

    __syncthreads();

    f32x4 acc[8];
    #pragma unroll
    for (int t = 0; t < 8; ++t) acc[t] = (f32x4){0.f, 0.f, 0.f, 0.f};

    #pragma unroll 2
    for (int t = 0; t < 8; ++t) {
        #pragma unroll
        for (int s = 0; s < 4; ++s) {
            short8 bvh = *(const short8*)&bh[t * 16 + m][s * 32 + kg * 8];
            short8 bvl = *(const short8*)&bl[t * 16 + m][s * 32 + kg * 8];
            acc[t] = __builtin_amdgcn_mfma_f32_16x16x32_bf16(avh[s], bvh, acc[t], 0, 0, 0);
            acc[t] = __builtin_amdgcn_mfma_f32_16x16x32_bf16(avh[s], bvl, acc[t], 0, 0, 0);
            acc[t] = __builtin_amdgcn_mfma_f32_16x16x32_bf16(avl[s], bvh, acc[t], 0, 0, 0);
        }
    }

    const int col = lane & 15, rb = (lane >> 4) * 4;
    #pragma unroll
    for (int r = 0; r < 4; ++r) {
        int row = rowbase + rb + r;
        if (row < n) {
            float d = dinv[row];
            __half* hrow = hs + (size_t)row * FEAT;
            #pragma unroll
            for (int t = 0; t < 8; ++t)
                hrow[t * 16 + col] = __float2half(acc[t][r] * d);
        }
    }
}

// ---- aggregation: out = act( dinv[i]*(hs[i] + sum hs[src]) + b ) -----------
// Round-11: latency-depth rework. agg was at 50% fabric BW, 25% VALU -> load-
// latency bound with only 8 rows in flight. Now: peel to 16B-aligned edge
// list, fetch indices as int4 scalar loads, keep 16 gathers in flight per
// wave (one full L3-hit latency window covers the mean degree of 16), 8
// independent accumulators.

__global__ __launch_bounds__(256)
void agg_kernel(const __half* __restrict__ hs, const int* __restrict__ indptr,
                const int* __restrict__ ssrc, const float* __restrict__ dinv,
                const float* __restrict__ bias, float* __restrict__ outf,
                unsigned short* __restrict__ outh, unsigned short* __restrict__ outl,
                int n, int do_relu) {
    int wid = threadIdx.x >> 6, lane = threadIdx.x & 63;
    int node = blockIdx.x * 4 + wid;
    if (node >= n) return;
    node = __builtin_amdgcn_readfirstlane(node);

    const __half2* hs2 = (const __half2*)hs;
    const __half2* hp = hs2 + lane;                       // per-lane base

    int start = __builtin_amdgcn_readfirstlane(indptr[node]);
    int end   = __builtin_amdgcn_readfirstlane(indptr[node + 1]);

    float2 a0 = __half22float2(hp[(size_t)node * 64]);    // self-loop, issued first
    float2 a1 = {0.f, 0.f}, a2 = {0.f, 0.f}, a3 = {0.f, 0.f};
    float2 a4 = {0.f, 0.f}, a5 = {0.f, 0.f}, a6 = {0.f, 0.f}, a7 = {0.f, 0.f};

    const int* sp = ssrc + start;
    int cnt = end - start;

    // peel to 16-byte alignment so index fetches are aligned int4
    int pre = (4 - (start & 3)) & 3;
    if (pre > cnt) pre = cnt;
    for (int j = 0; j < pre; ++j) {
        int s = __builtin_amdgcn_readfirstlane(sp[j]);
        float2 v = __half22float2(hp[(size_t)s * 64]);
        a1.x += v.x; a1.y += v.y;
    }
    sp += pre; cnt -= pre;

    int j = 0;
    for (; j + 16 <= cnt; j += 16) {
        int4 q0 = *(const int4*)(sp + j);
        int4 q1 = *(const int4*)(sp + j + 4);
        int4 q2 = *(const int4*)(sp + j + 8);
        int4 q3 = *(const int4*)(sp + j + 12);
        int s0  = __builtin_amdgcn_readfirstlane(q0.x);
        int s1  = __builtin_amdgcn_readfirstlane(q0.y);
        int s2  = __builtin_amdgcn_readfirstlane(q0.z);
        int s3  = __builtin_amdgcn_readfirstlane(q0.w);
        int s4  = __builtin_amdgcn_readfirstlane(q1.x);
        int s5  = __builtin_amdgcn_readfirstlane(q1.y);
        int s6  = __builtin_amdgcn_readfirstlane(q1.z);
        int s7  = __builtin_amdgcn_readfirstlane(q1.w);
        int s8  = __builtin_amdgcn_readfirstlane(q2.x);
        int s9  = __builtin_amdgcn_readfirstlane(q2.y);
        int s10 = __builtin_amdgcn_readfirstlane(q2.z);
        int s11 = __builtin_amdgcn_readfirstlane(q2.w);
        int s12 = __builtin_amdgcn_readfirstlane(q3.x);
        int s13 = __builtin_amdgcn_readfirstlane(q3.y);
        int s14 = __builtin_amdgcn_readfirstlane(q3.z);
        int s15 = __builtin_amdgcn_readfirstlane(q3.w);
        __half2 h0  = hp[(size_t)s0  * 64];
        __half2 h1  = hp[(size_t)s1  * 64];
        __half2 h2  = hp[(size_t)s2  * 64];
        __half2 h3  = hp[(size_t)s3  * 64];
        __half2 h4  = hp[(size_t)s4  * 64];
        __half2 h5  = hp[(size_t)s5  * 64];
        __half2 h6  = hp[(size_t)s6  * 64];
        __half2 h7  = hp[(size_t)s7  * 64];
        __half2 h8  = hp[(size_t)s8  * 64];
        __half2 h9  = hp[(size_t)s9  * 64];
        __half2 h10 = hp[(size_t)s10 * 64];
        __half2 h11 = hp[(size_t)s11 * 64];
        __half2 h12 = hp[(size_t)s12 * 64];
        __half2 h13 = hp[(size_t)s13 * 64];
        __half2 h14 = hp[(size_t)s14 * 64];
        __half2 h15 = hp[(size_t)s15 * 64];
        float2 v;
        v = __half22float2(h0);  a0.x += v.x; a0.y += v.y;
        v = __half22float2(h1);  a1.x += v.x; a1.y += v.y;
        v = __half22float2(h2);  a2.x += v.x; a2.y += v.y;
        v = __half22float2(h3);  a3.x += v.x; a3.y += v.y;
        v = __half22float2(h4);  a4.x += v.x; a4.y += v.y;
        v = __half22float2(h5);  a5.x += v.x; a5.y += v.y;
        v = __half22float2(h6);  a6.x += v.x; a6.y += v.y;
        v = __half22float2(h7);  a7.x += v.x; a7.y += v.y;
        v = __half22float2(h8);  a0.x += v.x; a0.y += v.y;
        v = __half22float2(h9);  a1.x += v.x; a1.y += v.y;
        v = __half22float2(h10); a2.x += v.x; a2.y += v.y;
        v = __half22float2(h11); a3.x += v.x; a3.y += v.y;
        v = __half22float2(h12); a4.x += v.x; a4.y += v.y;
        v = __half22float2(h13); a5.x += v.x; a5.y += v.y;
        v = __half22float2(h14); a6.x += v.x; a6.y += v.y;
        v = __half22float2(h15); a7.x += v.x; a7.y += v.y;
    }
    for (; j + 4 <= cnt; j += 4) {
        int4 q = *(const int4*)(sp + j);
        int s0 = __builtin_amdgcn_readfirstlane(q.x);
        int s1 = __builtin_amdgcn_readfirstlane(q.y);
        int s2 = __builtin_amdgcn_readfirstlane(q.z);
        int s3 = __builtin_amdgcn_readfirstlane(q.w);
        __half2 h0 = hp[(size_t)s0 * 64];
        __half2 h1 = hp[(size_t)s1 * 64];
        __half2 h2 = hp[(size_t)s2 * 64];
        __half2 h3 = hp[(size_t)s3 * 64];
        float2 v;
        v = __half22float2(h0); a4.x += v.x; a4.y += v.y;
        v = __half22float2(h1); a5.x += v.x; a5.y += v.y;
        v = __half22float2(h2); a6.x += v.x; a6.y += v.y;
        v = __half22float2(h3); a7.x += v.x; a7.y += v.y;
    }
    for (; j < cnt; ++j) {
        int s = __builtin_amdgcn_readfirstlane(sp[j]);
        float2 v = __half22float2(hp[(size_t)s * 64]);
        a2.x += v.x; a2.y += v.y;
    }

    float d = dinv[node];
    float2 bv = ((const float2*)bias)[lane];
    float ox = (((a0.x + a1.x) + (a2.x + a3.x)) + ((a4.x + a5.x) + (a6.x + a7.x))) * d + bv.x;
    float oy = (((a0.y + a1.y) + (a2.y + a3.y)) + ((a4.y + a5.y) + (a6.y + a7.y))) * d + bv.y;
    if (do_relu) { ox = fmaxf(ox, 0.f); oy = fmaxf(oy, 0.f); }

    if (outf) {
        float2 o; o.x = ox; o.y = oy;
        ((float2*)outf)[(size_t)node * 64 + lane] = o;
    } else {
        ushort2 h, l;
        h.x = f2bf(ox); l.x = f2bf(ox - bf2f(h.x));
        h.y = f2bf(oy); l.y = f2bf(oy - bf2f(h.y));
        ((ushort2*)outh)[(size_t)node * 64 + lane] = h;
        ((ushort2*)outl)[(size_t)node * 64 + lane] = l;
    }
}

// ---- launch ----------------------------------------------------------------

static inline size_t align256(size_t x) { return (x + 255) & ~(size_t)255; }

extern "C" void kernel_launch(void* const* d_in, const int* in_sizes, int n_in,
                              void* d_out, int out_size, void* d_ws, size_t ws_size,
                              hipStream_t stream) {
    const float* x  = (const float*)d_in[0];
    const int*   ei = (const int*)d_in[1];
    const float* W1 = (const float*)d_in[2];
    const float* b1 = (const float*)d_in[3];
    const float* W2 = (const float*)d_in[4];
    const float* b2 = (const float*)d_in[5];
    const float* W3 = (const float*)d_in[6];
    const float* b3 = (const float*)d_in[7];

    int n = in_sizes[0] / FEAT;      // 100000
    int E = in_sizes[1] / 2;         // 1600000
    const int* src = ei;
    const int* dst = ei + E;
    int NB = (n + BKT_G - 1) >> BKT_SHIFT;   // 782 buckets (n <= 131072 assumed)

    // workspace carve-up (~34 MB)
    char* w = (char*)d_ws;
    int* indptr  = (int*)w;                    w += align256((size_t)(n + 1) * 4);
    int* bcur    = (int*)w;                    w += align256((size_t)MAX_NB * 4);
    int* bbase   = (int*)w;                    w += align256((size_t)(MAX_NB + 1) * 4);
    float* dinv  = (float*)w;                  w += align256((size_t)n * 4);
    int* ssrc    = (int*)w;                    w += align256((size_t)E * 4);
    __half* hs   = (__half*)w;                 w += align256((size_t)n * FEAT * 2);
    unsigned short* wth = (unsigned short*)w;  w += align256((size_t)3 * 16384 * 2);
    unsigned short* wtl = (unsigned short*)w;  w += align256((size_t)3 * 16384 * 2);

    // bucket-strided packed edges alias hs (NB*BCAP*4 = 12.8 MB <= 25.6 MB;
    // tmp is dead before the first gemm writes hs)
    unsigned int* tmp = (unsigned int*)hs;

    // split activations live in d_out (exactly n*FEAT*4 bytes = two bf16 planes)
    unsigned short* xh = (unsigned short*)d_out;
    unsigned short* xl = xh + (size_t)n * FEAT;

    binit_kernel<<<(NB + 255) / 256, 256, 0, stream>>>(bcur, NB);
    bucket_scatter_kernel<<<(E + SC_EPB - 1) / SC_EPB, 256, 0, stream>>>(src, dst, bcur, tmp, E, NB);
    bscan_kernel<<<1, 1024, 0, stream>>>(bcur, bbase, indptr, n, NB, E);
    bucket_fill2_kernel<<<NB, 256, 0, stream>>>(tmp, bbase, indptr, dinv, ssrc, n);

    wprep_kernel<<<192, 256, 0, stream>>>(W1, W2, W3, wth, wtl);
    split_kernel<<<(n * FEAT / 4 + 255) / 256, 256, 0, stream>>>(x, xh, xl, n * FEAT / 4);

    for (int L = 0; L < 3; ++L) {
        const float* bb = (L == 0) ? b1 : (L == 1) ? b2 : b3;

        gemm_mfma<<<(n + 63) / 64, 256, 0, stream>>>(xh, xl, wth + (size_t)L * 16384,
                                                     wtl + (size_t)L * 16384, dinv, hs, n);
        if (L < 2) {
            agg_kernel<<<(n + 3) / 4, 256, 0, stream>>>(hs, indptr, ssrc, dinv, bb,
                                                        nullptr, xh, xl, n, 1);
        } else {
            agg_kernel<<<(n + 3) / 4, 256, 0, stream>>>(hs, indptr, ssrc, dinv, bb,
                                                        (float*)d_out, nullptr, nullptr, n, 0);
        }
    }
}

// Round 6
// 445.772 us; speedup vs baseline: 1.0261x; 1.0261x over previous
//
#include <hip/hip_runtime.h>
#include <hip/hip_bf16.h>
#include <hip/hip_fp16.h>

#define FEAT 128

typedef __attribute__((ext_vector_type(8))) short short8;
typedef __attribute__((ext_vector_type(4))) float f32x4;

static __device__ __forceinline__ unsigned short f2bf(float f) {
    unsigned int u = __float_as_uint(f);
    unsigned int r = (u + 0x7fffu + ((u >> 16) & 1u)) >> 16;
    return (unsigned short)r;
}
static __device__ __forceinline__ float bf2f(unsigned short b) {
    return __uint_as_float(((unsigned int)b) << 16);
}

// ---- CSR build -------------------------------------------------------------
// Fixed-capacity bucket scatter (round 10): binit(bcur[b]=b*CAP) ->
// bucket_scatter -> bscan(782 totals) -> bucket_fill2 (LDS hist + scan ->
// dinv, indptr, ssrc). No global histogram, no 100k scan.

#define BKT_SHIFT 7
#define BKT_G 128
#define MAX_NB 1024
#define BCAP 4096
#define SC_T 32
#define SC_EPB (256 * SC_T)   // 8192 edges per block

__global__ void binit_kernel(int* __restrict__ bcur, int NB) {
    int b = blockIdx.x * 256 + threadIdx.x;
    if (b < NB) bcur[b] = b * BCAP;
}

__global__ __launch_bounds__(256)
void bucket_scatter_kernel(const int* __restrict__ src, const int* __restrict__ dst,
                           int* __restrict__ bcur, unsigned int* __restrict__ tmp,
                           int E, int NB) {
    __shared__ int hist[MAX_NB];
    const int tid = threadIdx.x;
    const int ebase = blockIdx.x * SC_EPB;

    for (int i = tid; i < NB; i += 256) hist[i] = 0;
    __syncthreads();

    unsigned int pk[SC_T];    // packed (src,dst_local)
    unsigned int meta[SC_T];  // (bucket<<16) | local_rank ; 0xFFFFFFFF = invalid
    #pragma unroll
    for (int j = 0; j < SC_T; ++j) {
        int e = ebase + j * 256 + tid;
        if (e < E) {
            int s = src[e], d = dst[e];
            int b = d >> BKT_SHIFT;
            pk[j] = ((unsigned int)s << BKT_SHIFT) | (unsigned int)(d & (BKT_G - 1));
            int r = atomicAdd(&hist[b], 1);
            meta[j] = ((unsigned int)b << 16) | (unsigned int)r;
        } else {
            meta[j] = 0xFFFFFFFFu;
        }
    }
    __syncthreads();

    // one global atomic per (block,bucket); stash base back into hist
    for (int b = tid; b < NB; b += 256) {
        int c = hist[b];
        if (c > 0) hist[b] = atomicAdd(&bcur[b], c);
    }
    __syncthreads();

    #pragma unroll
    for (int j = 0; j < SC_T; ++j) {
        if (meta[j] != 0xFFFFFFFFu) {
            int b = meta[j] >> 16;
            int r = (int)(meta[j] & 0xFFFFu);
            tmp[hist[b] + r] = pk[j];
        }
    }
}

// exclusive scan of the 782 bucket totals (bcur[b]-b*CAP); writes bbase[0..NB]
// and indptr[n]=E. Single block, 1024 threads (NB <= 1024).
__global__ __launch_bounds__(1024)
void bscan_kernel(const int* __restrict__ bcur, int* __restrict__ bbase,
                  int* __restrict__ indptr, int n, int NB, int E) {
    __shared__ int swave[16];
    int tid = threadIdx.x, lane = tid & 63, wid = tid >> 6;
    int c = (tid < NB) ? (bcur[tid] - tid * BCAP) : 0;
    int x = c;
    #pragma unroll
    for (int off = 1; off < 64; off <<= 1) {
        int y = __shfl_up(x, off);
        if (lane >= off) x += y;
    }
    if (lane == 63) swave[wid] = x;
    __syncthreads();
    if (wid == 0 && lane < 16) {
        int s = swave[lane];
        #pragma unroll
        for (int off = 1; off < 16; off <<= 1) {
            int y = __shfl_up(s, off);
            if (lane >= off) s += y;
        }
        swave[lane] = s;
    }
    __syncthreads();
    int waveoff = (wid > 0) ? swave[wid - 1] : 0;
    if (tid <= NB) bbase[tid] = waveoff + x - c;   // exclusive prefix
    if (tid == 0) indptr[n] = E;
}

// block b: count local dst in LDS, emit dinv+indptr, scan, scatter ssrc.
__global__ __launch_bounds__(256)
void bucket_fill2_kernel(const unsigned int* __restrict__ tmp, const int* __restrict__ bbase,
                         int* __restrict__ indptr, float* __restrict__ dinv,
                         int* __restrict__ ssrc, int n) {
    __shared__ int cnt[BKT_G];
    __shared__ int cur[BKT_G];
    __shared__ int wtot;
    const int tid = threadIdx.x;
    const int b = blockIdx.x;
    const int nodebase = b * BKT_G;
    const int base_g = bbase[b];
    const int scnt = bbase[b + 1] - base_g;
    const unsigned int* tp = tmp + (size_t)b * BCAP;

    if (tid < BKT_G) cnt[tid] = 0;
    __syncthreads();
    for (int e = tid; e < scnt; e += 256)
        atomicAdd(&cnt[tp[e] & (BKT_G - 1)], 1);
    __syncthreads();

    int c = 0, x = 0;
    if (tid < BKT_G) {
        int lane = tid & 63;
        c = cnt[tid];
        x = c;
        #pragma unroll
        for (int off = 1; off < 64; off <<= 1) {
            int y = __shfl_up(x, off);
            if (lane >= off) x += y;
        }
    }
    if (tid == 63) wtot = x;   // wave0 inclusive total
    __syncthreads();
    if (tid < BKT_G) {
        int excl = x - c + ((tid >= 64) ? wtot : 0);
        int node = nodebase + tid;
        if (node < n) {
            dinv[node]   = rsqrtf((float)(c + 1));
            indptr[node] = base_g + excl;
        }
        cur[tid] = base_g + excl;
    }
    __syncthreads();
    for (int e = tid; e < scnt; e += 256) {
        unsigned int v = tp[e];
        int pos = atomicAdd(&cur[v & (BKT_G - 1)], 1);
        ssrc[pos] = (int)(v >> BKT_SHIFT);
    }
}

// ---- bf16x2 split prep -----------------------------------------------------

__global__ void split_kernel(const float* __restrict__ in, unsigned short* __restrict__ xh,
                             unsigned short* __restrict__ xl, int total4) {
    int i = blockIdx.x * 256 + threadIdx.x;
    if (i >= total4) return;
    float4 v = ((const float4*)in)[i];
    ushort4 h, l;
    h.x = f2bf(v.x); l.x = f2bf(v.x - bf2f(h.x));
    h.y = f2bf(v.y); l.y = f2bf(v.y - bf2f(h.y));
    h.z = f2bf(v.z); l.z = f2bf(v.z - bf2f(h.z));
    h.w = f2bf(v.w); l.w = f2bf(v.w - bf2f(h.w));
    ((ushort4*)xh)[i] = h;
    ((ushort4*)xl)[i] = l;
}

__global__ void wprep_kernel(const float* __restrict__ W1, const float* __restrict__ W2,
                             const float* __restrict__ W3, unsigned short* __restrict__ wth,
                             unsigned short* __restrict__ wtl) {
    int idx = blockIdx.x * 256 + threadIdx.x;   // 3 * 16384
    int l = idx >> 14, t = idx & 16383;
    int nn = t >> 7, kk = t & 127;
    const float* W = (l == 0) ? W1 : (l == 1) ? W2 : W3;
    float v = W[kk * 128 + nn];
    unsigned short h = f2bf(v);
    wth[idx] = h;
    wtl[idx] = f2bf(v - bf2f(h));
}

// ---- GEMM (split-bf16 MFMA, B staged in LDS): hs = (in @ W) * dinv, fp16 out

__global__ __launch_bounds__(256)
void gemm_mfma(const unsigned short* __restrict__ xh, const unsigned short* __restrict__ xl,
               const unsigned short* __restrict__ wth, const unsigned short* __restrict__ wtl,
               const float* __restrict__ dinv, __half* __restrict__ hs, int n) {
    __shared__ unsigned short bh[128][136];
    __shared__ unsigned short bl[128][136];

    const int tid = threadIdx.x;
    const int wave = tid >> 6, lane = tid & 63;
    const int rowbase = blockIdx.x * 64 + wave * 16;
    const int m = lane & 15, kg = lane >> 4;

    // stage B: thread -> row n0 = tid>>1, half kk0 = (tid&1)*64
    {
        const int n0 = tid >> 1, kk0 = (tid & 1) * 64;
        const unsigned short* gh = wth + (size_t)n0 * FEAT + kk0;
        const unsigned short* gl = wtl + (size_t)n0 * FEAT + kk0;
        #pragma unroll
        for (int j = 0; j < 8; ++j) {
            *(short8*)&bh[n0][kk0 + j * 8] = *(const short8*)(gh + j * 8);
            *(short8*)&bl[n0][kk0 + j * 8] = *(const short8*)(gl + j * 8);
        }
    }

    // A fragments (loaded while staging is in flight)
    int arow = rowbase + m;
    if (arow > n - 1) arow = n - 1;          // clamp; clamped rows never stored
    const size_t aoff = (size_t)arow * FEAT + kg * 8;
    short8 avh[4], avl[4];
    #pragma unroll
    for (int s = 0; s < 4; ++s) {
        avh[s] = *(const short8*)(xh + aoff + s * 32);
        avl[s] = *(const short8*)(xl + aoff + s * 32);
    }

    __syncthreads();

    f32x4 acc[8];
    #pragma unroll
    for (int t = 0; t < 8; ++t) acc[t] = (f32x4){0.f, 0.f, 0.f, 0.f};

    #pragma unroll 2
    for (int t = 0; t < 8; ++t) {
        #pragma unroll
        for (int s = 0; s < 4; ++s) {
            short8 bvh = *(const short8*)&bh[t * 16 + m][s * 32 + kg * 8];
            short8 bvl = *(const short8*)&bl[t * 16 + m][s * 32 + kg * 8];
            acc[t] = __builtin_amdgcn_mfma_f32_16x16x32_bf16(avh[s], bvh, acc[t], 0, 0, 0);
            acc[t] = __builtin_amdgcn_mfma_f32_16x16x32_bf16(avh[s], bvl, acc[t], 0, 0, 0);
            acc[t] = __builtin_amdgcn_mfma_f32_16x16x32_bf16(avl[s], bvh, acc[t], 0, 0, 0);
        }
    }

    const int col = lane & 15, rb = (lane >> 4) * 4;
    #pragma unroll
    for (int r = 0; r < 4; ++r) {
        int row = rowbase + rb + r;
        if (row < n) {
            float d = dinv[row];
            __half* hrow = hs + (size_t)row * FEAT;
            #pragma unroll
            for (int t = 0; t < 8; ++t)
                hrow[t * 16 + col] = __float2half(acc[t][r] * d);
        }
    }
}

// ---- aggregation: out = act( dinv[i]*(hs[i] + sum hs[src]) + b ) -----------
// Round-12: one node per HALF-WAVE (32 lanes x uint2 = 256 B row). Doubles
// node-level gather concurrency per wave slot vs round-4 (2 streams x 8 deep)
// WITHOUT the VGPR/SGPR blowup that sank round-5 (occupancy 61%). Plain
// vector loads; indices are uniform within a half-wave (1-2 requests/load).

#define ACC4(A, U) { __half2 lo_ = *(__half2*)&(U).x, hi_ = *(__half2*)&(U).y; \
    float2 l_ = __half22float2(lo_), h_ = __half22float2(hi_);                 \
    (A).x += l_.x; (A).y += l_.y; (A).z += h_.x; (A).w += h_.y; }

__global__ __launch_bounds__(256)
void agg_kernel(const __half* __restrict__ hs, const int* __restrict__ indptr,
                const int* __restrict__ ssrc, const float* __restrict__ dinv,
                const float* __restrict__ bias, float* __restrict__ outf,
                unsigned short* __restrict__ outh, unsigned short* __restrict__ outl,
                int n, int do_relu) {
    const int wid = threadIdx.x >> 6, lane = threadIdx.x & 63;
    const int hh = lane >> 5, c32 = lane & 31;
    int node = blockIdx.x * 8 + wid * 2 + hh;
    const bool alive = node < n;
    if (!alive) node = n - 1;

    const uint2* hq = ((const uint2*)hs) + c32;   // 8B chunk c32 of each row

    int start = indptr[node], end = indptr[node + 1];
    int cnt = alive ? (end - start) : 0;
    const int* sp = ssrc + start;

    float4 a0 = {0.f, 0.f, 0.f, 0.f}, a1 = a0, a2 = a0, a3 = a0;
    uint2 su = hq[(size_t)node * 32];             // self-loop row
    ACC4(a0, su);

    int j = 0;
    for (; j + 8 <= cnt; j += 8) {
        int s0 = sp[j + 0], s1 = sp[j + 1], s2 = sp[j + 2], s3 = sp[j + 3];
        int s4 = sp[j + 4], s5 = sp[j + 5], s6 = sp[j + 6], s7 = sp[j + 7];
        uint2 v0 = hq[(size_t)s0 * 32];
        uint2 v1 = hq[(size_t)s1 * 32];
        uint2 v2 = hq[(size_t)s2 * 32];
        uint2 v3 = hq[(size_t)s3 * 32];
        uint2 v4 = hq[(size_t)s4 * 32];
        uint2 v5 = hq[(size_t)s5 * 32];
        uint2 v6 = hq[(size_t)s6 * 32];
        uint2 v7 = hq[(size_t)s7 * 32];
        ACC4(a0, v0); ACC4(a1, v1); ACC4(a2, v2); ACC4(a3, v3);
        ACC4(a0, v4); ACC4(a1, v5); ACC4(a2, v6); ACC4(a3, v7);
    }
    for (; j + 2 <= cnt; j += 2) {
        int s0 = sp[j], s1 = sp[j + 1];
        uint2 v0 = hq[(size_t)s0 * 32];
        uint2 v1 = hq[(size_t)s1 * 32];
        ACC4(a0, v0); ACC4(a1, v1);
    }
    if (j < cnt) {
        int s = sp[j];
        uint2 v = hq[(size_t)s * 32];
        ACC4(a2, v);
    }

    float d = dinv[node];
    float4 bv = ((const float4*)bias)[c32];
    float4 o;
    o.x = ((a0.x + a1.x) + (a2.x + a3.x)) * d + bv.x;
    o.y = ((a0.y + a1.y) + (a2.y + a3.y)) * d + bv.y;
    o.z = ((a0.z + a1.z) + (a2.z + a3.z)) * d + bv.z;
    o.w = ((a0.w + a1.w) + (a2.w + a3.w)) * d + bv.w;
    if (do_relu) {
        o.x = fmaxf(o.x, 0.f); o.y = fmaxf(o.y, 0.f);
        o.z = fmaxf(o.z, 0.f); o.w = fmaxf(o.w, 0.f);
    }

    if (alive) {
        if (outf) {
            ((float4*)outf)[(size_t)node * 32 + c32] = o;
        } else {
            ushort4 h, l;
            h.x = f2bf(o.x); l.x = f2bf(o.x - bf2f(h.x));
            h.y = f2bf(o.y); l.y = f2bf(o.y - bf2f(h.y));
            h.z = f2bf(o.z); l.z = f2bf(o.z - bf2f(h.z));
            h.w = f2bf(o.w); l.w = f2bf(o.w - bf2f(h.w));
            ((ushort4*)outh)[(size_t)node * 32 + c32] = h;
            ((ushort4*)outl)[(size_t)node * 32 + c32] = l;
        }
    }
}

// ---- launch ----------------------------------------------------------------

static inline size_t align256(size_t x) { return (x + 255) & ~(size_t)255; }

extern "C" void kernel_launch(void* const* d_in, const int* in_sizes, int n_in,
                              void* d_out, int out_size, void* d_ws, size_t ws_size,
                              hipStream_t stream) {
    const float* x  = (const float*)d_in[0];
    const int*   ei = (const int*)d_in[1];
    const float* W1 = (const float*)d_in[2];
    const float* b1 = (const float*)d_in[3];
    const float* W2 = (const float*)d_in[4];
    const float* b2 = (const float*)d_in[5];
    const float* W3 = (const float*)d_in[6];
    const float* b3 = (const float*)d_in[7];

    int n = in_sizes[0] / FEAT;      // 100000
    int E = in_sizes[1] / 2;         // 1600000
    const int* src = ei;
    const int* dst = ei + E;
    int NB = (n + BKT_G - 1) >> BKT_SHIFT;   // 782 buckets (n <= 131072 assumed)

    // workspace carve-up (~34 MB)
    char* w = (char*)d_ws;
    int* indptr  = (int*)w;                    w += align256((size_t)(n + 1) * 4);
    int* bcur    = (int*)w;                    w += align256((size_t)MAX_NB * 4);
    int* bbase   = (int*)w;                    w += align256((size_t)(MAX_NB + 1) * 4);
    float* dinv  = (float*)w;                  w += align256((size_t)n * 4);
    int* ssrc    = (int*)w;                    w += align256((size_t)E * 4);
    __half* hs   = (__half*)w;                 w += align256((size_t)n * FEAT * 2);
    unsigned short* wth = (unsigned short*)w;  w += align256((size_t)3 * 16384 * 2);
    unsigned short* wtl = (unsigned short*)w;  w += align256((size_t)3 * 16384 * 2);

    // bucket-strided packed edges alias hs (NB*BCAP*4 = 12.8 MB <= 25.6 MB;
    // tmp is dead before the first gemm writes hs)
    unsigned int* tmp = (unsigned int*)hs;

    // split activations live in d_out (exactly n*FEAT*4 bytes = two bf16 planes)
    unsigned short* xh = (unsigned short*)d_out;
    unsigned short* xl = xh + (size_t)n * FEAT;

    binit_kernel<<<(NB + 255) / 256, 256, 0, stream>>>(bcur, NB);
    bucket_scatter_kernel<<<(E + SC_EPB - 1) / SC_EPB, 256, 0, stream>>>(src, dst, bcur, tmp, E, NB);
    bscan_kernel<<<1, 1024, 0, stream>>>(bcur, bbase, indptr, n, NB, E);
    bucket_fill2_kernel<<<NB, 256, 0, stream>>>(tmp, bbase, indptr, dinv, ssrc, n);

    wprep_kernel<<<192, 256, 0, stream>>>(W1, W2, W3, wth, wtl);
    split_kernel<<<(n * FEAT / 4 + 255) / 256, 256, 0, stream>>>(x, xh, xl, n * FEAT / 4);

    for (int L = 0; L < 3; ++L) {
        const float* bb = (L == 0) ? b1 : (L == 1) ? b2 : b3;

        gemm_mfma<<<(n + 63) / 64, 256, 0, stream>>>(xh, xl, wth + (size_t)L * 16384,
                                                     wtl + (size_t)L * 16384, dinv, hs, n);
        if (L < 2) {
            agg_kernel<<<(n + 7) / 8, 256, 0, stream>>>(hs, indptr, ssrc, dinv, bb,
                                                        nullptr, xh, xl, n, 1);
        } else {
            agg_kernel<<<(n + 7) / 8, 256, 0, stream>>>(hs, indptr, ssrc, dinv, bb,
                                                        (float*)d_out, nullptr, nullptr, n, 0);
        }
    }
}

// Round 7
// 405.673 us; speedup vs baseline: 1.1275x; 1.0988x over previous
//
#include <hip/hip_runtime.h>
#include <hip/hip_bf16.h>
#include <hip/hip_fp16.h>

#define FEAT 128

typedef __attribute__((ext_vector_type(8))) short short8;
typedef __attribute__((ext_vector_type(4))) float f32x4;

static __device__ __forceinline__ unsigned short f2bf(float f) {
    unsigned int u = __float_as_uint(f);
    unsigned int r = (u + 0x7fffu + ((u >> 16) & 1u)) >> 16;
    return (unsigned short)r;
}
static __device__ __forceinline__ float bf2f(unsigned short b) {
    return __uint_as_float(((unsigned int)b) << 16);
}

// ---- CSR build -------------------------------------------------------------
// Fixed-capacity bucket scatter: binit(bcur[b]=b*CAP) -> bucket_scatter ->
// bscan(782 totals, merged with wprep) -> bucket_fill2 (LDS hist + scan ->
// dinv, indptr, ssrc).

#define BKT_SHIFT 7
#define BKT_G 128
#define MAX_NB 1024
#define BCAP 4096
#define SC_T 32
#define SC_EPB (256 * SC_T)   // 8192 edges per block

__global__ void binit_kernel(int* __restrict__ bcur, int NB) {
    int b = blockIdx.x * 256 + threadIdx.x;
    if (b < NB) bcur[b] = b * BCAP;
}

__global__ __launch_bounds__(256)
void bucket_scatter_kernel(const int* __restrict__ src, const int* __restrict__ dst,
                           int* __restrict__ bcur, unsigned int* __restrict__ tmp,
                           int E, int NB) {
    __shared__ int hist[MAX_NB];
    const int tid = threadIdx.x;
    const int ebase = blockIdx.x * SC_EPB;

    for (int i = tid; i < NB; i += 256) hist[i] = 0;
    __syncthreads();

    unsigned int pk[SC_T];    // packed (src,dst_local)
    unsigned int meta[SC_T];  // (bucket<<16) | local_rank ; 0xFFFFFFFF = invalid
    #pragma unroll
    for (int j = 0; j < SC_T; ++j) {
        int e = ebase + j * 256 + tid;
        if (e < E) {
            int s = src[e], d = dst[e];
            int b = d >> BKT_SHIFT;
            pk[j] = ((unsigned int)s << BKT_SHIFT) | (unsigned int)(d & (BKT_G - 1));
            int r = atomicAdd(&hist[b], 1);
            meta[j] = ((unsigned int)b << 16) | (unsigned int)r;
        } else {
            meta[j] = 0xFFFFFFFFu;
        }
    }
    __syncthreads();

    // one global atomic per (block,bucket); stash base back into hist
    for (int b = tid; b < NB; b += 256) {
        int c = hist[b];
        if (c > 0) hist[b] = atomicAdd(&bcur[b], c);
    }
    __syncthreads();

    #pragma unroll
    for (int j = 0; j < SC_T; ++j) {
        if (meta[j] != 0xFFFFFFFFu) {
            int b = meta[j] >> 16;
            int r = (int)(meta[j] & 0xFFFFu);
            tmp[hist[b] + r] = pk[j];
        }
    }
}

// block 0: exclusive scan of bucket totals (bcur[b]-b*CAP) -> bbase[0..NB],
// indptr[n]=E. blocks 1..48: weight prep (transpose + bf16 hi/lo split).
__global__ __launch_bounds__(1024)
void bscan_wprep_kernel(const int* __restrict__ bcur, int* __restrict__ bbase,
                        int* __restrict__ indptr, int n, int NB, int E,
                        const float* __restrict__ W1, const float* __restrict__ W2,
                        const float* __restrict__ W3, unsigned short* __restrict__ wth,
                        unsigned short* __restrict__ wtl) {
    if (blockIdx.x == 0) {
        __shared__ int swave[16];
        int tid = threadIdx.x, lane = tid & 63, wid = tid >> 6;
        int c = (tid < NB) ? (bcur[tid] - tid * BCAP) : 0;
        int x = c;
        #pragma unroll
        for (int off = 1; off < 64; off <<= 1) {
            int y = __shfl_up(x, off);
            if (lane >= off) x += y;
        }
        if (lane == 63) swave[wid] = x;
        __syncthreads();
        if (wid == 0 && lane < 16) {
            int s = swave[lane];
            #pragma unroll
            for (int off = 1; off < 16; off <<= 1) {
                int y = __shfl_up(s, off);
                if (lane >= off) s += y;
            }
            swave[lane] = s;
        }
        __syncthreads();
        int waveoff = (wid > 0) ? swave[wid - 1] : 0;
        if (tid <= NB) bbase[tid] = waveoff + x - c;   // exclusive prefix
        if (tid == 0) indptr[n] = E;
    } else {
        int idx = (blockIdx.x - 1) * 1024 + threadIdx.x;   // 3 * 16384 total
        if (idx < 3 * 16384) {
            int l = idx >> 14, t = idx & 16383;
            int nn = t >> 7, kk = t & 127;
            const float* W = (l == 0) ? W1 : (l == 1) ? W2 : W3;
            float v = W[kk * 128 + nn];
            unsigned short h = f2bf(v);
            wth[idx] = h;
            wtl[idx] = f2bf(v - bf2f(h));
        }
    }
}

// block b: count local dst in LDS, emit dinv+indptr, scan, scatter ssrc.
__global__ __launch_bounds__(256)
void bucket_fill2_kernel(const unsigned int* __restrict__ tmp, const int* __restrict__ bbase,
                         int* __restrict__ indptr, float* __restrict__ dinv,
                         int* __restrict__ ssrc, int n) {
    __shared__ int cnt[BKT_G];
    __shared__ int cur[BKT_G];
    __shared__ int wtot;
    const int tid = threadIdx.x;
    const int b = blockIdx.x;
    const int nodebase = b * BKT_G;
    const int base_g = bbase[b];
    const int scnt = bbase[b + 1] - base_g;
    const unsigned int* tp = tmp + (size_t)b * BCAP;

    if (tid < BKT_G) cnt[tid] = 0;
    __syncthreads();
    for (int e = tid; e < scnt; e += 256)
        atomicAdd(&cnt[tp[e] & (BKT_G - 1)], 1);
    __syncthreads();

    int c = 0, x = 0;
    if (tid < BKT_G) {
        int lane = tid & 63;
        c = cnt[tid];
        x = c;
        #pragma unroll
        for (int off = 1; off < 64; off <<= 1) {
            int y = __shfl_up(x, off);
            if (lane >= off) x += y;
        }
    }
    if (tid == 63) wtot = x;   // wave0 inclusive total
    __syncthreads();
    if (tid < BKT_G) {
        int excl = x - c + ((tid >= 64) ? wtot : 0);
        int node = nodebase + tid;
        if (node < n) {
            dinv[node]   = rsqrtf((float)(c + 1));
            indptr[node] = base_g + excl;
        }
        cur[tid] = base_g + excl;
    }
    __syncthreads();
    for (int e = tid; e < scnt; e += 256) {
        unsigned int v = tp[e];
        int pos = atomicAdd(&cur[v & (BKT_G - 1)], 1);
        ssrc[pos] = (int)(v >> BKT_SHIFT);
    }
}

// ---- GEMM (split-bf16 MFMA, B staged in LDS): hs = (in @ W) * dinv, fp16 out
// Round-13: 128-row M-tile, 512 threads (8 waves). LDS 69.6 KB -> 2 blocks/CU
// = 16 waves/CU (was 8), half the blocks, half the B-restaging. Layer 1 reads
// f32 x directly and splits to bf16 hi/lo in-register (bit-identical to the
// deleted split_kernel; saves its 102 MB of traffic).

template <bool F32IN>
__global__ __launch_bounds__(512)
void gemm_mfma(const float* __restrict__ xf, const unsigned short* __restrict__ xh,
               const unsigned short* __restrict__ xl,
               const unsigned short* __restrict__ wth, const unsigned short* __restrict__ wtl,
               const float* __restrict__ dinv, __half* __restrict__ hs, int n) {
    __shared__ unsigned short bh[128][136];
    __shared__ unsigned short bl[128][136];

    const int tid = threadIdx.x;
    const int wave = tid >> 6, lane = tid & 63;
    const int rowbase = blockIdx.x * 128 + wave * 16;
    const int m = lane & 15, kg = lane >> 4;

    // stage B: 512 threads, 128 B each. plane p = tid>>8 (0=hi,1=lo)
    {
        const int p = tid >> 8, t = tid & 255;
        const int n0 = t >> 1, kk0 = (t & 1) * 64;
        const unsigned short* g = (p ? wtl : wth) + (size_t)n0 * FEAT + kk0;
        unsigned short (*dstp)[136] = p ? bl : bh;
        #pragma unroll
        for (int j = 0; j < 8; ++j)
            *(short8*)&dstp[n0][kk0 + j * 8] = *(const short8*)(g + j * 8);
    }

    // A fragments (loaded while staging is in flight)
    int arow = rowbase + m;
    if (arow > n - 1) arow = n - 1;          // clamp; clamped rows never stored
    short8 avh[4], avl[4];
    if constexpr (F32IN) {
        const float* ap = xf + (size_t)arow * FEAT + kg * 8;
        #pragma unroll
        for (int s = 0; s < 4; ++s) {
            float4 f0 = *(const float4*)(ap + s * 32);
            float4 f1 = *(const float4*)(ap + s * 32 + 4);
            float fv[8] = {f0.x, f0.y, f0.z, f0.w, f1.x, f1.y, f1.z, f1.w};
            short8 h, l;
            #pragma unroll
            for (int k = 0; k < 8; ++k) {
                unsigned short hb = f2bf(fv[k]);
                h[k] = (short)hb;
                l[k] = (short)f2bf(fv[k] - bf2f(hb));
            }
            avh[s] = h; avl[s] = l;
        }
    } else {
        const size_t aoff = (size_t)arow * FEAT + kg * 8;
        #pragma unroll
        for (int s = 0; s < 4; ++s) {
            avh[s] = *(const short8*)(xh + aoff + s * 32);
            avl[s] = *(const short8*)(xl + aoff + s * 32);
        }
    }

    __syncthreads();

    f32x4 acc[8];
    #pragma unroll
    for (int t = 0; t < 8; ++t) acc[t] = (f32x4){0.f, 0.f, 0.f, 0.f};

    #pragma unroll 2
    for (int t = 0; t < 8; ++t) {
        #pragma unroll
        for (int s = 0; s < 4; ++s) {
            short8 bvh = *(const short8*)&bh[t * 16 + m][s * 32 + kg * 8];
            short8 bvl = *(const short8*)&bl[t * 16 + m][s * 32 + kg * 8];
            acc[t] = __builtin_amdgcn_mfma_f32_16x16x32_bf16(avh[s], bvh, acc[t], 0, 0, 0);
            acc[t] = __builtin_amdgcn_mfma_f32_16x16x32_bf16(avh[s], bvl, acc[t], 0, 0, 0);
            acc[t] = __builtin_amdgcn_mfma_f32_16x16x32_bf16(avl[s], bvh, acc[t], 0, 0, 0);
        }
    }

    const int col = lane & 15, rb = (lane >> 4) * 4;
    #pragma unroll
    for (int r = 0; r < 4; ++r) {
        int row = rowbase + rb + r;
        if (row < n) {
            float d = dinv[row];
            __half* hrow = hs + (size_t)row * FEAT;
            #pragma unroll
            for (int t = 0; t < 8; ++t)
                hrow[t * 16 + col] = __float2half(acc[t][r] * d);
        }
    }
}

// ---- aggregation: out = act( dinv[i]*(hs[i] + sum hs[src]) + b ) -----------
// Round-4 form (best measured: 63.1 us): one node per wave, scalar-pipe
// indptr/ssrc via readfirstlane, 8 gathers in flight, 4 accumulators.

__global__ __launch_bounds__(256)
void agg_kernel(const __half* __restrict__ hs, const int* __restrict__ indptr,
                const int* __restrict__ ssrc, const float* __restrict__ dinv,
                const float* __restrict__ bias, float* __restrict__ outf,
                unsigned short* __restrict__ outh, unsigned short* __restrict__ outl,
                int n, int do_relu) {
    int wid = threadIdx.x >> 6, lane = threadIdx.x & 63;
    int node = blockIdx.x * 4 + wid;
    if (node >= n) return;
    node = __builtin_amdgcn_readfirstlane(node);

    const __half2* hs2 = (const __half2*)hs;
    float2 a0 = __half22float2(hs2[(size_t)node * 64 + lane]);  // self-loop term
    float2 a1 = {0.f, 0.f}, a2 = {0.f, 0.f}, a3 = {0.f, 0.f};

    int start = __builtin_amdgcn_readfirstlane(indptr[node]);
    int end   = __builtin_amdgcn_readfirstlane(indptr[node + 1]);
    const int* sp = ssrc + start;
    int cnt = end - start;

    int j = 0;
    for (; j + 8 <= cnt; j += 8) {
        int s0 = __builtin_amdgcn_readfirstlane(sp[j + 0]);
        int s1 = __builtin_amdgcn_readfirstlane(sp[j + 1]);
        int s2 = __builtin_amdgcn_readfirstlane(sp[j + 2]);
        int s3 = __builtin_amdgcn_readfirstlane(sp[j + 3]);
        int s4 = __builtin_amdgcn_readfirstlane(sp[j + 4]);
        int s5 = __builtin_amdgcn_readfirstlane(sp[j + 5]);
        int s6 = __builtin_amdgcn_readfirstlane(sp[j + 6]);
        int s7 = __builtin_amdgcn_readfirstlane(sp[j + 7]);
        float2 v0 = __half22float2(hs2[(size_t)s0 * 64 + lane]);
        float2 v1 = __half22float2(hs2[(size_t)s1 * 64 + lane]);
        float2 v2 = __half22float2(hs2[(size_t)s2 * 64 + lane]);
        float2 v3 = __half22float2(hs2[(size_t)s3 * 64 + lane]);
        float2 v4 = __half22float2(hs2[(size_t)s4 * 64 + lane]);
        float2 v5 = __half22float2(hs2[(size_t)s5 * 64 + lane]);
        float2 v6 = __half22float2(hs2[(size_t)s6 * 64 + lane]);
        float2 v7 = __half22float2(hs2[(size_t)s7 * 64 + lane]);
        a0.x += v0.x; a0.y += v0.y;
        a1.x += v1.x; a1.y += v1.y;
        a2.x += v2.x; a2.y += v2.y;
        a3.x += v3.x; a3.y += v3.y;
        a0.x += v4.x; a0.y += v4.y;
        a1.x += v5.x; a1.y += v5.y;
        a2.x += v6.x; a2.y += v6.y;
        a3.x += v7.x; a3.y += v7.y;
    }
    for (; j + 2 <= cnt; j += 2) {
        int s0 = __builtin_amdgcn_readfirstlane(sp[j + 0]);
        int s1 = __builtin_amdgcn_readfirstlane(sp[j + 1]);
        float2 v0 = __half22float2(hs2[(size_t)s0 * 64 + lane]);
        float2 v1 = __half22float2(hs2[(size_t)s1 * 64 + lane]);
        a0.x += v0.x; a0.y += v0.y;
        a1.x += v1.x; a1.y += v1.y;
    }
    if (j < cnt) {
        int s = __builtin_amdgcn_readfirstlane(sp[j]);
        float2 v = __half22float2(hs2[(size_t)s * 64 + lane]);
        a2.x += v.x; a2.y += v.y;
    }

    float d = dinv[node];
    float2 bv = ((const float2*)bias)[lane];
    float ox = ((a0.x + a1.x) + (a2.x + a3.x)) * d + bv.x;
    float oy = ((a0.y + a1.y) + (a2.y + a3.y)) * d + bv.y;
    if (do_relu) { ox = fmaxf(ox, 0.f); oy = fmaxf(oy, 0.f); }

    if (outf) {
        float2 o; o.x = ox; o.y = oy;
        ((float2*)outf)[(size_t)node * 64 + lane] = o;
    } else {
        ushort2 h, l;
        h.x = f2bf(ox); l.x = f2bf(ox - bf2f(h.x));
        h.y = f2bf(oy); l.y = f2bf(oy - bf2f(h.y));
        ((ushort2*)outh)[(size_t)node * 64 + lane] = h;
        ((ushort2*)outl)[(size_t)node * 64 + lane] = l;
    }
}

// ---- launch ----------------------------------------------------------------

static inline size_t align256(size_t x) { return (x + 255) & ~(size_t)255; }

extern "C" void kernel_launch(void* const* d_in, const int* in_sizes, int n_in,
                              void* d_out, int out_size, void* d_ws, size_t ws_size,
                              hipStream_t stream) {
    const float* x  = (const float*)d_in[0];
    const int*   ei = (const int*)d_in[1];
    const float* W1 = (const float*)d_in[2];
    const float* b1 = (const float*)d_in[3];
    const float* W2 = (const float*)d_in[4];
    const float* b2 = (const float*)d_in[5];
    const float* W3 = (const float*)d_in[6];
    const float* b3 = (const float*)d_in[7];

    int n = in_sizes[0] / FEAT;      // 100000
    int E = in_sizes[1] / 2;         // 1600000
    const int* src = ei;
    const int* dst = ei + E;
    int NB = (n + BKT_G - 1) >> BKT_SHIFT;   // 782 buckets (n <= 131072 assumed)

    // workspace carve-up (~34 MB)
    char* w = (char*)d_ws;
    int* indptr  = (int*)w;                    w += align256((size_t)(n + 1) * 4);
    int* bcur    = (int*)w;                    w += align256((size_t)MAX_NB * 4);
    int* bbase   = (int*)w;                    w += align256((size_t)(MAX_NB + 1) * 4);
    float* dinv  = (float*)w;                  w += align256((size_t)n * 4);
    int* ssrc    = (int*)w;                    w += align256((size_t)E * 4);
    __half* hs   = (__half*)w;                 w += align256((size_t)n * FEAT * 2);
    unsigned short* wth = (unsigned short*)w;  w += align256((size_t)3 * 16384 * 2);
    unsigned short* wtl = (unsigned short*)w;  w += align256((size_t)3 * 16384 * 2);

    // bucket-strided packed edges alias hs (NB*BCAP*4 = 12.8 MB <= 25.6 MB;
    // tmp is dead before the first gemm writes hs)
    unsigned int* tmp = (unsigned int*)hs;

    // split activations live in d_out (exactly n*FEAT*4 bytes = two bf16 planes)
    unsigned short* xh = (unsigned short*)d_out;
    unsigned short* xl = xh + (size_t)n * FEAT;

    binit_kernel<<<(NB + 255) / 256, 256, 0, stream>>>(bcur, NB);
    bucket_scatter_kernel<<<(E + SC_EPB - 1) / SC_EPB, 256, 0, stream>>>(src, dst, bcur, tmp, E, NB);
    bscan_wprep_kernel<<<49, 1024, 0, stream>>>(bcur, bbase, indptr, n, NB, E,
                                                W1, W2, W3, wth, wtl);
    bucket_fill2_kernel<<<NB, 256, 0, stream>>>(tmp, bbase, indptr, dinv, ssrc, n);

    const int gemm_grid = (n + 127) / 128;
    for (int L = 0; L < 3; ++L) {
        const float* bb = (L == 0) ? b1 : (L == 1) ? b2 : b3;

        if (L == 0) {
            gemm_mfma<true><<<gemm_grid, 512, 0, stream>>>(x, nullptr, nullptr,
                                                           wth, wtl, dinv, hs, n);
        } else {
            gemm_mfma<false><<<gemm_grid, 512, 0, stream>>>(nullptr, xh, xl,
                                                            wth + (size_t)L * 16384,
                                                            wtl + (size_t)L * 16384,
                                                            dinv, hs, n);
        }
        if (L < 2) {
            agg_kernel<<<(n + 3) / 4, 256, 0, stream>>>(hs, indptr, ssrc, dinv, bb,
                                                        nullptr, xh, xl, n, 1);
        } else {
            agg_kernel<<<(n + 3) / 4, 256, 0, stream>>>(hs, indptr, ssrc, dinv, bb,
                                                        (float*)d_out, nullptr, nullptr, n, 0);
        }
    }
}